// Round 1
// 1882.017 us; speedup vs baseline: 1.1875x; 1.1875x over previous
//
#include <hip/hip_runtime.h>

typedef __bf16 bf16;
typedef __attribute__((ext_vector_type(8))) __bf16 bf16x8;
typedef __attribute__((ext_vector_type(4))) float f32x4;

#define SEQ 4096
#define DM  1024
#define NH  16
#define DH  64

// ---------------------------------------------------------------------------
// Generic bt-GEMM: C[m][n] = scale * sum_k A[m][k]*B[n][k] + bias[n]
// A: fp32 or bf16 (converted during LDS staging), B: bf16 (pre-transposed),
// C: fp32 or bf16. MFMA 16x16x32 bf16, fp32 accumulate.
// Verified layouts (learn_hip m89/m91/m92): A/B frag: lane holds
// [m|n = lane&15][k = (lane>>4)*8 + j] (8 contiguous bf16);
// C/D: col = lane&15, row = (lane>>4)*4 + reg.
// ---------------------------------------------------------------------------
template<int BM, int BN, int BK, int WM, int WN, int TM, int TN,
         typename AT, typename CT>
__global__ __launch_bounds__(WM*WN*64) void gemm_bt(
    const AT* __restrict__ A, long lda, long sAb,
    const bf16* __restrict__ B, long ldb, long sBb,
    CT* __restrict__ C, long ldc, long sCb,
    const float* __restrict__ bias, float scale, int K)
{
  static_assert(BM == WM*16*TM && BN == WN*16*TN, "tile mismatch");
  constexpr int NT = WM*WN*64;
  constexpr int LDP = BK + 8;              // +8 bf16 pad: 2-way-max bank alias
  __shared__ bf16 As[BM][LDP];
  __shared__ bf16 Bs[BN][LDP];

  const int tid  = threadIdx.x;
  const int lane = tid & 63;
  const int wave = tid >> 6;
  const int wm   = wave % WM;
  const int wn   = wave / WM;
  const int tr   = lane & 15;
  const int quad = lane >> 4;

  A += (long)blockIdx.z * sAb + (long)blockIdx.x * BM * lda;
  B += (long)blockIdx.z * sBb + (long)blockIdx.y * BN * ldb;
  C += (long)blockIdx.z * sCb;

  f32x4 acc[TM][TN] = {};

  for (int k0 = 0; k0 < K; k0 += BK) {
    if constexpr (sizeof(AT) == 4) {
      #pragma unroll
      for (int i = tid; i < BM*(BK/4); i += NT) {
        int r = i / (BK/4), c = (i % (BK/4)) * 4;
        const float4 f = *(const float4*)(A + (long)r*lda + k0 + c);
        As[r][c+0] = (bf16)f.x; As[r][c+1] = (bf16)f.y;
        As[r][c+2] = (bf16)f.z; As[r][c+3] = (bf16)f.w;
      }
    } else {
      #pragma unroll
      for (int i = tid; i < BM*(BK/8); i += NT) {
        int r = i / (BK/8), c = (i % (BK/8)) * 8;
        *(bf16x8*)&As[r][c] = *(const bf16x8*)(A + (long)r*lda + k0 + c);
      }
    }
    #pragma unroll
    for (int i = tid; i < BN*(BK/8); i += NT) {
      int r = i / (BK/8), c = (i % (BK/8)) * 8;
      *(bf16x8*)&Bs[r][c] = *(const bf16x8*)(B + (long)r*ldb + k0 + c);
    }
    __syncthreads();

    #pragma unroll
    for (int kk = 0; kk < BK; kk += 32) {
      bf16x8 af[TM], bfr[TN];
      #pragma unroll
      for (int i = 0; i < TM; ++i)
        af[i] = *(const bf16x8*)&As[wm*16*TM + i*16 + tr][kk + quad*8];
      #pragma unroll
      for (int j = 0; j < TN; ++j)
        bfr[j] = *(const bf16x8*)&Bs[wn*16*TN + j*16 + tr][kk + quad*8];
      #pragma unroll
      for (int i = 0; i < TM; ++i)
        #pragma unroll
        for (int j = 0; j < TN; ++j)
          acc[i][j] = __builtin_amdgcn_mfma_f32_16x16x32_bf16(af[i], bfr[j], acc[i][j], 0, 0, 0);
    }
    __syncthreads();
  }

  #pragma unroll
  for (int i = 0; i < TM; ++i) {
    #pragma unroll
    for (int j = 0; j < TN; ++j) {
      const int row0 = blockIdx.x*BM + wm*16*TM + i*16 + quad*4;
      const int col  = blockIdx.y*BN + wn*16*TN + j*16 + tr;
      const float bv = bias ? bias[col] : 0.f;
      #pragma unroll
      for (int r = 0; r < 4; ++r) {
        float v = acc[i][j][r] * scale + bv;
        C[(long)(row0 + r)*ldc + col] = (CT)v;
      }
    }
  }
}

// ---------------------------------------------------------------------------
// Transpose src[R][Cc] -> dst[Cc][R], casting to bf16. block (32,8).
// ---------------------------------------------------------------------------
template<typename T>
__global__ void transpose_to_bf16(const T* __restrict__ src, bf16* __restrict__ dst,
                                  int R, int Cc)
{
  __shared__ T tile[32][33];
  const int c0 = blockIdx.x * 32, r0 = blockIdx.y * 32;
  const int tx = threadIdx.x, ty = threadIdx.y;
  #pragma unroll
  for (int i = ty; i < 32; i += 8)
    tile[i][tx] = src[(long)(r0 + i)*Cc + c0 + tx];
  __syncthreads();
  #pragma unroll
  for (int i = ty; i < 32; i += 8)
    dst[(long)(c0 + i)*R + r0 + tx] = (bf16)tile[tx][i];
}

// ---------------------------------------------------------------------------
// Fused scores+softmax+PV (flash-style, score recompute).
// Block: one head (blockIdx.y), one 64-row Q block (blockIdx.x). 256 thr.
// Pass 1: per-lane online (max, expsum) over 32 K-tiles of 128 cols.
//         Combine: shfl over the 16 tr-lanes, then LDS over the 2 wave-cols.
// Pass 2: recompute score tile, p = exp(s-m)/l, write attn (fp32, once),
//         p->bf16 into LDS, accumulate O += P @ V^T via MFMA.
// Waves 2x2 over the 64(M) x 128(N) score tile: TM=2, TN=4.
// PV: 64(M) x 64(Nd), waves 2x2: TM=2, TN=2, K=128 per tile.
// ---------------------------------------------------------------------------
__global__ __launch_bounds__(256) void fused_attn(
    const bf16* __restrict__ Qb,   // [SEQ][DM], already projected
    const bf16* __restrict__ Kb,   // [SEQ][DM]
    const bf16* __restrict__ Vt,   // [DM][SEQ]  (V^T)
    float* __restrict__ attn,      // [NH][SEQ][SEQ]
    bf16* __restrict__ Cc)         // [SEQ][DM]  concat output
{
  constexpr int BM = 64;          // q rows per block
  constexpr int BN = 128;         // key cols per tile
  constexpr int NTILE = SEQ / BN; // 32

  __shared__ bf16 Qs[BM][72];     //  9.2 KB (row stride 144 B: 2-way alias max)
  __shared__ bf16 Ks[BN][72];     // 18.4 KB
  __shared__ bf16 Vs[DH][136];    // 17.4 KB (row stride 272 B: 2-way alias max)
  __shared__ bf16 Ps[BM][136];    // 17.4 KB
  __shared__ float Msh[2][BM];
  __shared__ float Lsh[2][BM];

  const int tid  = threadIdx.x;
  const int lane = tid & 63;
  const int wave = tid >> 6;
  const int wm   = wave & 1;      // row half
  const int wn   = wave >> 1;     // col half
  const int tr   = lane & 15;
  const int quad = lane >> 4;

  const int h  = blockIdx.y;
  const int qb = blockIdx.x;

  const bf16* Qg = Qb + (long)(qb*BM)*DM + h*DH;
  const bf16* Kg = Kb + h*DH;
  const bf16* Vg = Vt + (long)(h*DH)*SEQ;
  float* attng   = attn + (long)h*SEQ*SEQ + (long)(qb*BM)*SEQ;

  // stage Q once, folding the 1/sqrt(64)=0.125 scale (exact in bf16: pow2)
  #pragma unroll
  for (int i = tid; i < BM*8; i += 256) {
    int r = i >> 3, c = (i & 7) * 8;
    bf16x8 vv = *(const bf16x8*)(Qg + (long)r*DM + c);
    #pragma unroll
    for (int e = 0; e < 8; ++e) vv[e] = (bf16)((float)vv[e] * 0.125f);
    *(bf16x8*)&Qs[r][c] = vv;
  }

  float m_[2][4], l_[2][4];
  #pragma unroll
  for (int ii = 0; ii < 2; ++ii)
    #pragma unroll
    for (int r = 0; r < 4; ++r) { m_[ii][r] = -1e30f; l_[ii][r] = 0.f; }

  // ---------------- pass 1: row stats ----------------
  for (int kb = 0; kb < NTILE; ++kb) {
    #pragma unroll
    for (int i = tid; i < BN*8; i += 256) {
      int r = i >> 3, c = (i & 7) * 8;
      *(bf16x8*)&Ks[r][c] = *(const bf16x8*)(Kg + (long)(kb*BN + r)*DM + c);
    }
    __syncthreads();           // also covers initial Qs staging (kb==0)

    f32x4 acc[2][4] = {};
    #pragma unroll
    for (int kk = 0; kk < DH; kk += 32) {
      bf16x8 af[2], bfr[4];
      #pragma unroll
      for (int ii = 0; ii < 2; ++ii)
        af[ii] = *(const bf16x8*)&Qs[wm*32 + ii*16 + tr][kk + quad*8];
      #pragma unroll
      for (int j = 0; j < 4; ++j)
        bfr[j] = *(const bf16x8*)&Ks[wn*64 + j*16 + tr][kk + quad*8];
      #pragma unroll
      for (int ii = 0; ii < 2; ++ii)
        #pragma unroll
        for (int j = 0; j < 4; ++j)
          acc[ii][j] = __builtin_amdgcn_mfma_f32_16x16x32_bf16(af[ii], bfr[j], acc[ii][j], 0, 0, 0);
    }
    // per-lane online update over this tile's 4 cols per row (no cross-lane)
    #pragma unroll
    for (int ii = 0; ii < 2; ++ii)
      #pragma unroll
      for (int r = 0; r < 4; ++r) {
        float mx = fmaxf(fmaxf(acc[ii][0][r], acc[ii][1][r]),
                         fmaxf(acc[ii][2][r], acc[ii][3][r]));
        float mn = fmaxf(m_[ii][r], mx);
        float sc = __expf(m_[ii][r] - mn);
        float s  = __expf(acc[ii][0][r] - mn) + __expf(acc[ii][1][r] - mn)
                 + __expf(acc[ii][2][r] - mn) + __expf(acc[ii][3][r] - mn);
        l_[ii][r] = l_[ii][r] * sc + s;
        m_[ii][r] = mn;
      }
    __syncthreads();           // Ks safe to restage
  }

  // combine across the 16 tr-lanes (pairwise online merge)
  #pragma unroll
  for (int ii = 0; ii < 2; ++ii)
    #pragma unroll
    for (int r = 0; r < 4; ++r) {
      float mv = m_[ii][r], lv = l_[ii][r];
      #pragma unroll
      for (int o = 1; o <= 8; o <<= 1) {
        float m2 = __shfl_xor(mv, o, 64);
        float l2 = __shfl_xor(lv, o, 64);
        float mo = fmaxf(mv, m2);
        lv = lv * __expf(mv - mo) + l2 * __expf(m2 - mo);
        mv = mo;
      }
      m_[ii][r] = mv; l_[ii][r] = lv;
    }
  // combine across the two wave-columns via LDS
  if (tr == 0) {
    #pragma unroll
    for (int ii = 0; ii < 2; ++ii)
      #pragma unroll
      for (int r = 0; r < 4; ++r) {
        int row = wm*32 + ii*16 + quad*4 + r;
        Msh[wn][row] = m_[ii][r];
        Lsh[wn][row] = l_[ii][r];
      }
  }
  __syncthreads();
  float linv[2][4];
  #pragma unroll
  for (int ii = 0; ii < 2; ++ii)
    #pragma unroll
    for (int r = 0; r < 4; ++r) {
      int row = wm*32 + ii*16 + quad*4 + r;
      float ma = Msh[0][row], mb = Msh[1][row];
      float mo = fmaxf(ma, mb);
      float lt = Lsh[0][row] * __expf(ma - mo) + Lsh[1][row] * __expf(mb - mo);
      m_[ii][r]  = mo;
      linv[ii][r] = 1.f / lt;
    }

  // ---------------- pass 2: recompute + write attn + PV ----------------
  f32x4 oacc[2][2] = {};
  for (int kb = 0; kb < NTILE; ++kb) {
    #pragma unroll
    for (int i = tid; i < BN*8; i += 256) {
      int r = i >> 3, c = (i & 7) * 8;
      *(bf16x8*)&Ks[r][c] = *(const bf16x8*)(Kg + (long)(kb*BN + r)*DM + c);
    }
    #pragma unroll
    for (int i = tid; i < DH*16; i += 256) {
      int r = i >> 4, c = (i & 15) * 8;
      *(bf16x8*)&Vs[r][c] = *(const bf16x8*)(Vg + (long)r*SEQ + kb*BN + c);
    }
    __syncthreads();

    f32x4 acc[2][4] = {};
    #pragma unroll
    for (int kk = 0; kk < DH; kk += 32) {
      bf16x8 af[2], bfr[4];
      #pragma unroll
      for (int ii = 0; ii < 2; ++ii)
        af[ii] = *(const bf16x8*)&Qs[wm*32 + ii*16 + tr][kk + quad*8];
      #pragma unroll
      for (int j = 0; j < 4; ++j)
        bfr[j] = *(const bf16x8*)&Ks[wn*64 + j*16 + tr][kk + quad*8];
      #pragma unroll
      for (int ii = 0; ii < 2; ++ii)
        #pragma unroll
        for (int j = 0; j < 4; ++j)
          acc[ii][j] = __builtin_amdgcn_mfma_f32_16x16x32_bf16(af[ii], bfr[j], acc[ii][j], 0, 0, 0);
    }

    // p = exp(s - m) / l ; write attn (fp32, only write of this data), Ps (bf16)
    #pragma unroll
    for (int ii = 0; ii < 2; ++ii) {
      #pragma unroll
      for (int j = 0; j < 4; ++j) {
        const int col = wn*64 + j*16 + tr;
        #pragma unroll
        for (int r = 0; r < 4; ++r) {
          const int row = wm*32 + ii*16 + quad*4 + r;
          float p = __expf(acc[ii][j][r] - m_[ii][r]) * linv[ii][r];
          attng[(long)row*SEQ + kb*BN + col] = p;
          Ps[row][col] = (bf16)p;
        }
      }
    }
    __syncthreads();           // Ps complete; Ks reads done

    // PV: O[64][64] += Ps[64][128] @ Vs^T (Vs is [d][k])
    #pragma unroll
    for (int kk = 0; kk < BN; kk += 32) {
      bf16x8 pa[2], vb[2];
      #pragma unroll
      for (int ii = 0; ii < 2; ++ii)
        pa[ii] = *(const bf16x8*)&Ps[wm*32 + ii*16 + tr][kk + quad*8];
      #pragma unroll
      for (int jd = 0; jd < 2; ++jd)
        vb[jd] = *(const bf16x8*)&Vs[wn*32 + jd*16 + tr][kk + quad*8];
      #pragma unroll
      for (int ii = 0; ii < 2; ++ii)
        #pragma unroll
        for (int jd = 0; jd < 2; ++jd)
          oacc[ii][jd] = __builtin_amdgcn_mfma_f32_16x16x32_bf16(pa[ii], vb[jd], oacc[ii][jd], 0, 0, 0);
    }
    __syncthreads();           // Ps/Vs safe to restage
  }

  // write concat: Cc[s][h*64 + d]
  #pragma unroll
  for (int ii = 0; ii < 2; ++ii) {
    #pragma unroll
    for (int jd = 0; jd < 2; ++jd) {
      const int col = h*DH + wn*32 + jd*16 + tr;
      #pragma unroll
      for (int r = 0; r < 4; ++r) {
        const int row = qb*BM + wm*32 + ii*16 + quad*4 + r;
        Cc[(long)row*DM + col] = (bf16)oacc[ii][jd][r];
      }
    }
  }
}

// ---------------------------------------------------------------------------
extern "C" void kernel_launch(void* const* d_in, const int* in_sizes, int n_in,
                              void* d_out, int out_size, void* d_ws, size_t ws_size,
                              hipStream_t stream)
{
  const float* q  = (const float*)d_in[0];
  const float* k  = (const float*)d_in[1];
  const float* v  = (const float*)d_in[2];
  const float* Wq = (const float*)d_in[3];
  const float* bq = (const float*)d_in[4];
  const float* Wk = (const float*)d_in[5];
  const float* bk = (const float*)d_in[6];
  const float* Wv = (const float*)d_in[7];
  const float* bv = (const float*)d_in[8];
  const float* Wo = (const float*)d_in[9];
  const float* bo = (const float*)d_in[10];

  float* out  = (float*)d_out;                 // [4096][1024] fp32
  float* attn = out + (long)SEQ * DM;          // [16][4096][4096] fp32

  // workspace layout (48 MB total)
  char* ws = (char*)d_ws;
  bf16* WqT = (bf16*)(ws + 0l*(1l<<21));       // [1024][1024] bf16, Wt[n][k]=W[k][n]
  bf16* WkT = (bf16*)(ws + 1l*(1l<<21));
  bf16* WvT = (bf16*)(ws + 2l*(1l<<21));
  bf16* WoT = (bf16*)(ws + 3l*(1l<<21));
  bf16* Qb  = (bf16*)(ws + 1l*(1l<<23));       // [4096][1024] bf16 projected
  bf16* Kb  = (bf16*)(ws + 2l*(1l<<23));
  bf16* Vb  = (bf16*)(ws + 3l*(1l<<23));
  bf16* Vt  = (bf16*)(ws + 4l*(1l<<23));       // [1024][4096] = V^T
  bf16* Cc  = (bf16*)(ws + 5l*(1l<<23));       // [4096][1024] concat

  const dim3 tb(32, 8);

  // 1) weights -> bf16 transposed (bt layout)
  transpose_to_bf16<float><<<dim3(32, 32), tb, 0, stream>>>(Wq, WqT, DM, DM);
  transpose_to_bf16<float><<<dim3(32, 32), tb, 0, stream>>>(Wk, WkT, DM, DM);
  transpose_to_bf16<float><<<dim3(32, 32), tb, 0, stream>>>(Wv, WvT, DM, DM);
  transpose_to_bf16<float><<<dim3(32, 32), tb, 0, stream>>>(Wo, WoT, DM, DM);

  // 2) projections: Qb = q@Wq+bq (fp32 A converted in staging, bf16 out)
  gemm_bt<128,128,64,2,2,4,4,float,bf16><<<dim3(32, 8, 1), 256, 0, stream>>>(
      q, DM, 0, WqT, DM, 0, Qb, DM, 0, bq, 1.f, DM);
  gemm_bt<128,128,64,2,2,4,4,float,bf16><<<dim3(32, 8, 1), 256, 0, stream>>>(
      k, DM, 0, WkT, DM, 0, Kb, DM, 0, bk, 1.f, DM);
  gemm_bt<128,128,64,2,2,4,4,float,bf16><<<dim3(32, 8, 1), 256, 0, stream>>>(
      v, DM, 0, WvT, DM, 0, Vb, DM, 0, bv, 1.f, DM);

  // 3) V^T for the PV step (B operand needs [n][k] = [d][s])
  transpose_to_bf16<bf16><<<dim3(DM/32, SEQ/32), tb, 0, stream>>>(Vb, Vt, SEQ, DM);

  // 4-6) fused: scores + softmax + PV. attn written exactly once (normalized).
  fused_attn<<<dim3(SEQ/64, NH), 256, 0, stream>>>(Qb, Kb, Vt, attn, Cc);

  // 7) out = concat @ Wo + bo
  gemm_bt<128,128,64,2,2,4,4,bf16,float><<<dim3(32, 8, 1), 256, 0, stream>>>(
      Cc, DM, 0, WoT, DM, 0, out, DM, 0, bo, 1.f, DM);
}